// Round 1
// baseline (4332.530 us; speedup 1.0000x reference)
//
#include <hip/hip_runtime.h>
#include <hip/hip_bf16.h>
#include <math.h>

// ---------------------------------------------------------------------------
// Tiled fp32 GEMM: C[M,N] = A[M,K] * B (+bias, optional tanh epilogue)
// TRANSB=1: B is (N,K) row-major, use B[n*K+k]  (i.e. A @ B^T)
// TRANSB=0: B is (K,N) row-major, use B[k*N+n]  (i.e. A @ B)
// M must be a multiple of 64; K a multiple of 16; N a multiple of 4.
// ---------------------------------------------------------------------------
#define GBK 16
#define LDT 68

template<int TRANSB, int ACT>
__global__ __launch_bounds__(256) void gemm_f32(
    const float* __restrict__ A, const float* __restrict__ B,
    const float* __restrict__ bias, float* __restrict__ C,
    int M, int N, int K)
{
  __shared__ float As[GBK * LDT];
  __shared__ float Bs[GBK * LDT];
  const int tid = threadIdx.x;
  const int bx = blockIdx.x, by = blockIdx.y;
  const int tx = tid & 15, ty = tid >> 4;
  const int row0 = by * 64, col0 = bx * 64;
  float acc[4][4] = {{0.f,0.f,0.f,0.f},{0.f,0.f,0.f,0.f},
                     {0.f,0.f,0.f,0.f},{0.f,0.f,0.f,0.f}};
  const int lm  = tid >> 2;          // 0..63
  const int lk4 = (tid & 3) << 2;    // 0,4,8,12
  const int lkr = tid >> 4;          // 0..15
  const int ln4 = (tid & 15) << 2;   // 0..60

  for (int k0 = 0; k0 < K; k0 += GBK) {
    // A tile (64 x 16), stored transposed As[k][m]
    float4 av = *(const float4*)(A + (size_t)(row0 + lm) * K + k0 + lk4);
    As[(lk4+0)*LDT + lm] = av.x;
    As[(lk4+1)*LDT + lm] = av.y;
    As[(lk4+2)*LDT + lm] = av.z;
    As[(lk4+3)*LDT + lm] = av.w;
    if constexpr (TRANSB) {
      float4 bv = make_float4(0.f,0.f,0.f,0.f);
      if (col0 + lm < N)
        bv = *(const float4*)(B + (size_t)(col0 + lm) * K + k0 + lk4);
      Bs[(lk4+0)*LDT + lm] = bv.x;
      Bs[(lk4+1)*LDT + lm] = bv.y;
      Bs[(lk4+2)*LDT + lm] = bv.z;
      Bs[(lk4+3)*LDT + lm] = bv.w;
    } else {
      float4 bv = make_float4(0.f,0.f,0.f,0.f);
      if (col0 + ln4 < N)
        bv = *(const float4*)(B + (size_t)(k0 + lkr) * N + col0 + ln4);
      *(float4*)(&Bs[lkr*LDT + ln4]) = bv;
    }
    __syncthreads();
    #pragma unroll
    for (int k = 0; k < GBK; ++k) {
      float4 a4 = *(const float4*)(&As[k*LDT + ty*4]);
      float4 b4 = *(const float4*)(&Bs[k*LDT + tx*4]);
      float am[4] = {a4.x, a4.y, a4.z, a4.w};
      float bm[4] = {b4.x, b4.y, b4.z, b4.w};
      #pragma unroll
      for (int i = 0; i < 4; ++i)
        #pragma unroll
        for (int j = 0; j < 4; ++j)
          acc[i][j] = fmaf(am[i], bm[j], acc[i][j]);
    }
    __syncthreads();
  }
  #pragma unroll
  for (int i = 0; i < 4; ++i) {
    const int r = row0 + ty*4 + i;
    #pragma unroll
    for (int j = 0; j < 4; ++j) {
      const int c = col0 + tx*4 + j;
      if (c < N) {
        float v = acc[i][j];
        if (bias) v += bias[c];
        if (ACT == 1) v = tanhf(v);
        C[(size_t)r * N + c] = v;
      }
    }
  }
}

// ---------------------------------------------------------------------------
// Elementwise prep: builds decay (in place of wt), k_final, v_final (in place
// of vt), aa=-kk, bb=kk*a.  One block per (b,t) row; thread handles 8
// consecutive channels (all inside one head of 64).
// ---------------------------------------------------------------------------
__global__ __launch_bounds__(256) void prep_kernel(
    const float* __restrict__ k_buf, const float* __restrict__ v_buf,
    float* wt_decay, const float* __restrict__ at, float* vt_vf,
    const float* __restrict__ v_first,
    const float* __restrict__ w0, const float* __restrict__ a0,
    const float* __restrict__ v0, const float* __restrict__ k_k,
    const float* __restrict__ k_a,
    float* __restrict__ kf, float* __restrict__ aaq, float* __restrict__ bbq)
{
  const int row = blockIdx.x;          // b*1024 + t
  const int tid = threadIdx.x;
  const int c0 = tid << 3;             // 8 channels per thread
  const int h = tid >> 3;              // head index (8 threads per head)
  const int kvoff = (h >> 2) << 6;     // kv head base (n_rep = 4)
  const size_t base = (size_t)row * 2048;
  const size_t kvrow = (size_t)row * 512;
  float kr[8], kkr[8];
  float ss = 0.f;
  #pragma unroll
  for (int e = 0; e < 8; ++e) {
    const int c = c0 + e;
    const float kv = k_buf[kvrow + kvoff + (c & 63)];
    kr[e] = kv;
    const float t = kv * k_k[c];
    kkr[e] = t;
    ss = fmaf(t, t, ss);
  }
  // sum of squares over the 8 threads covering this head (same wave)
  ss += __shfl_xor(ss, 1);
  ss += __shfl_xor(ss, 2);
  ss += __shfl_xor(ss, 4);
  const float inv = 1.f / fmaxf(sqrtf(ss), 1e-12f);
  #pragma unroll
  for (int e = 0; e < 8; ++e) {
    const int c = c0 + e;
    const size_t idx = base + c;
    const float kk = kkr[e] * inv;
    const float a = 1.f / (1.f + expf(-(a0[c] + at[idx])));
    // decay = exp(-exp(w_raw)); exp(w_raw) = exp(-0.6)*sigmoid(u)
    const float u = w0[c] + wt_decay[idx];
    const float sig_u = 1.f / (1.f + expf(-u));
    wt_decay[idx] = expf(-0.5488116360940264f * sig_u);
    kf[idx] = kr[e] * fmaf(a - 1.f, k_a[c], 1.f);
    const float vr = v_buf[kvrow + kvoff + (c & 63)];
    const float sv = 1.f / (1.f + expf(-(v0[c] + vt_vf[idx])));
    vt_vf[idx] = vr + (v_first[idx] - vr) * sv;
    aaq[idx] = -kk;
    bbq[idx] = kk * a;
  }
}

// ---------------------------------------------------------------------------
// RWKV-7 recurrent scan.  One wave (64 threads) per (b,h); lane i owns state
// row S[i][0:64] in registers.  Per-step vectors broadcast through LDS.
// ---------------------------------------------------------------------------
__global__ __launch_bounds__(64) void scan_kernel(
    const float* __restrict__ rB, const float* __restrict__ dB,
    const float* __restrict__ kB, const float* __restrict__ vB,
    const float* __restrict__ aB, const float* __restrict__ bB,
    const float* __restrict__ state, float* __restrict__ y)
{
  const int bh = blockIdx.x;           // b*32 + h
  const int b = bh >> 5, h = bh & 31;
  const int lane = threadIdx.x;
  __shared__ float a_s[64];
  __shared__ float4 vec[64];           // (decay, bb, k, r) per column
  float S[64];
  {
    const float* sp = state + ((size_t)bh * 64 + lane) * 64;
    #pragma unroll
    for (int k = 0; k < 64; ++k) S[k] = sp[k];
  }
  const size_t rowbase = ((size_t)b * 1024) * 2048 + (size_t)h * 64 + lane;
  float ra = aB[rowbase], rd = dB[rowbase], rb = bB[rowbase],
        rk = kB[rowbase], rr = rB[rowbase], rv = vB[rowbase];
  for (int t = 0; t < 1024; ++t) {
    a_s[lane] = ra;
    vec[lane] = make_float4(rd, rb, rk, rr);
    const float vi = rv;
    __syncthreads();
    if (t < 1023) {  // software-pipelined prefetch of step t+1
      const size_t o = rowbase + (size_t)(t + 1) * 2048;
      ra = aB[o]; rd = dB[o]; rb = bB[o]; rk = kB[o]; rr = rB[o]; rv = vB[o];
    }
    // sa_i = sum_k S[i][k] * aa[k]
    float s0 = 0.f, s1 = 0.f, s2 = 0.f, s3 = 0.f;
    const float4* a4p = (const float4*)a_s;
    #pragma unroll
    for (int q = 0; q < 16; ++q) {
      float4 a4 = a4p[q];
      s0 = fmaf(S[4*q+0], a4.x, s0);
      s1 = fmaf(S[4*q+1], a4.y, s1);
      s2 = fmaf(S[4*q+2], a4.z, s2);
      s3 = fmaf(S[4*q+3], a4.w, s3);
    }
    const float sa = (s0 + s1) + (s2 + s3);
    // S[i][k] = S*d + sa*bb + v_i*k ;  y_i = sum_k S_new[i][k]*r[k]
    float y0 = 0.f, y1 = 0.f, y2 = 0.f, y3 = 0.f;
    #pragma unroll
    for (int q = 0; q < 16; ++q) {
      float4 c0 = vec[4*q+0];
      float4 c1 = vec[4*q+1];
      float4 c2 = vec[4*q+2];
      float4 c3 = vec[4*q+3];
      S[4*q+0] = fmaf(S[4*q+0], c0.x, fmaf(sa, c0.y, vi * c0.z));
      y0 = fmaf(S[4*q+0], c0.w, y0);
      S[4*q+1] = fmaf(S[4*q+1], c1.x, fmaf(sa, c1.y, vi * c1.z));
      y1 = fmaf(S[4*q+1], c1.w, y1);
      S[4*q+2] = fmaf(S[4*q+2], c2.x, fmaf(sa, c2.y, vi * c2.z));
      y2 = fmaf(S[4*q+2], c2.w, y2);
      S[4*q+3] = fmaf(S[4*q+3], c3.x, fmaf(sa, c3.y, vi * c3.z));
      y3 = fmaf(S[4*q+3], c3.w, y3);
    }
    y[rowbase + (size_t)t * 2048] = (y0 + y1) + (y2 + y3);
    __syncthreads();
  }
}

// ---------------------------------------------------------------------------
// GroupNorm over (T,N) per (b,h) + bonus term, writes xx.
// ---------------------------------------------------------------------------
__global__ __launch_bounds__(256) void gnorm_kernel(
    const float* __restrict__ y, const float* __restrict__ rB,
    const float* __restrict__ kf, const float* __restrict__ vf,
    const float* __restrict__ r_k, const float* __restrict__ ln_w,
    const float* __restrict__ ln_b, float* __restrict__ xx)
{
  const int bh = blockIdx.x;
  const int b = bh >> 5, h = bh & 31;
  const int tid = threadIdx.x;
  const size_t base = ((size_t)b * 1024) * 2048 + (size_t)h * 64;
  float s = 0.f, ss = 0.f;
  for (int i = tid; i < 65536; i += 256) {
    const int t = i >> 6, n = i & 63;
    const float v = y[base + (size_t)t * 2048 + n];
    s += v;
    ss = fmaf(v, v, ss);
  }
  #pragma unroll
  for (int o = 1; o < 64; o <<= 1) {
    s  += __shfl_xor(s, o);
    ss += __shfl_xor(ss, o);
  }
  __shared__ float red[8];
  const int wid = tid >> 6;
  if ((tid & 63) == 0) { red[wid] = s; red[4 + wid] = ss; }
  __syncthreads();
  const float st  = red[0] + red[1] + red[2] + red[3];
  const float sst = red[4] + red[5] + red[6] + red[7];
  const float mean = st * (1.f / 65536.f);
  const float var  = sst * (1.f / 65536.f) - mean * mean;
  const float rstd = rsqrtf(var + 0.00064f);
  const int n0 = tid & 63;   // constant per thread (256 % 64 == 0)
  const float lw  = ln_w[h * 64 + n0];
  const float lb  = ln_b[h * 64 + n0];
  const float rkv = r_k [h * 64 + n0];
  for (int i = tid; i < 65536; i += 256) {
    const int t = i >> 6;
    const size_t idx = base + (size_t)t * 2048 + n0;
    float p = rB[idx] * kf[idx] * rkv;
    #pragma unroll
    for (int o = 1; o < 64; o <<= 1) p += __shfl_xor(p, o);
    const float yn = (y[idx] - mean) * rstd;
    xx[idx] = fmaf(yn, lw, lb) + p * vf[idx];
  }
}

// ---------------------------------------------------------------------------
extern "C" void kernel_launch(void* const* d_in, const int* in_sizes, int n_in,
                              void* d_out, int out_size, void* d_ws, size_t ws_size,
                              hipStream_t stream) {
  const float* x       = (const float*)d_in[0];
  const float* v_first = (const float*)d_in[1];
  const float* state   = (const float*)d_in[2];
  const float* Rw      = (const float*)d_in[3];
  const float* R_bias  = (const float*)d_in[4];
  const float* Kw      = (const float*)d_in[5];
  const float* K_bias  = (const float*)d_in[6];
  const float* Vw      = (const float*)d_in[7];
  const float* V_bias  = (const float*)d_in[8];
  const float* Ow      = (const float*)d_in[9];
  const float* O_bias  = (const float*)d_in[10];
  const float* w0      = (const float*)d_in[11];
  const float* w1      = (const float*)d_in[12];
  const float* w2      = (const float*)d_in[13];
  const float* a0      = (const float*)d_in[14];
  const float* a1      = (const float*)d_in[15];
  const float* a2      = (const float*)d_in[16];
  const float* v0      = (const float*)d_in[17];
  const float* v1      = (const float*)d_in[18];
  const float* v2      = (const float*)d_in[19];
  const float* k_k     = (const float*)d_in[20];
  const float* k_a     = (const float*)d_in[21];
  const float* r_k     = (const float*)d_in[22];
  const float* ln_w    = (const float*)d_in[23];
  const float* ln_b    = (const float*)d_in[24];

  float* ws = (float*)d_ws;
  float* r_buf = ws;                    // 4096*2048
  float* k_buf = r_buf + 8388608;       // 4096*512
  float* v_buf = k_buf + 2097152;       // 4096*512
  float* hw    = v_buf + 2097152;       // 4096*64 (tanh(x@w1))
  float* ha    = hw    + 262144;        // 4096*64
  float* hv    = ha    + 262144;        // 4096*32
  float* wt    = hv    + 131072;        // 4096*2048, becomes decay in place
  float* at    = wt    + 8388608;       // 4096*2048, becomes y after prep
  float* vt    = at    + 8388608;       // 4096*2048, becomes v_final in place
  float* kf    = vt    + 8388608;       // 4096*2048
  float* aaq   = kf    + 8388608;       // 4096*2048, becomes xx after scan
  float* bbq   = aaq   + 8388608;       // 4096*2048
  // total: 63,569,920 floats = 254.3 MB

  dim3 blk(256);
  // projections
  gemm_f32<1,0><<<dim3(32,64), blk, 0, stream>>>(x,  Rw, R_bias, r_buf, 4096, 2048, 2048);
  gemm_f32<1,0><<<dim3( 8,64), blk, 0, stream>>>(x,  Kw, K_bias, k_buf, 4096,  512, 2048);
  gemm_f32<1,0><<<dim3( 8,64), blk, 0, stream>>>(x,  Vw, V_bias, v_buf, 4096,  512, 2048);
  // low-rank stage 1
  gemm_f32<0,1><<<dim3( 1,64), blk, 0, stream>>>(x,  w1, nullptr, hw,   4096,   64, 2048);
  gemm_f32<0,0><<<dim3( 1,64), blk, 0, stream>>>(x,  a1, nullptr, ha,   4096,   64, 2048);
  gemm_f32<0,0><<<dim3( 1,64), blk, 0, stream>>>(x,  v1, nullptr, hv,   4096,   32, 2048);
  // low-rank stage 2
  gemm_f32<0,0><<<dim3(32,64), blk, 0, stream>>>(hw, w2, nullptr, wt,   4096, 2048,   64);
  gemm_f32<0,0><<<dim3(32,64), blk, 0, stream>>>(ha, a2, nullptr, at,   4096, 2048,   64);
  gemm_f32<0,0><<<dim3(32,64), blk, 0, stream>>>(hv, v2, nullptr, vt,   4096, 2048,   32);
  // elementwise prep
  prep_kernel<<<4096, 256, 0, stream>>>(k_buf, v_buf, wt, at, vt, v_first,
                                        w0, a0, v0, k_k, k_a, kf, aaq, bbq);
  // recurrent scan (y reuses `at`)
  float* ybuf = at;
  scan_kernel<<<128, 64, 0, stream>>>(r_buf, wt, kf, vt, aaq, bbq, state, ybuf);
  // group norm + bonus (xx reuses `aaq`)
  float* xxbuf = aaq;
  gnorm_kernel<<<128, 256, 0, stream>>>(ybuf, r_buf, kf, vt, r_k, ln_w, ln_b, xxbuf);
  // output projection
  gemm_f32<1,0><<<dim3(32,64), blk, 0, stream>>>(xxbuf, Ow, O_bias, (float*)d_out,
                                                 4096, 2048, 2048);
}

// Round 2
// 2114.691 us; speedup vs baseline: 2.0488x; 2.0488x over previous
//
#include <hip/hip_runtime.h>
#include <hip/hip_bf16.h>
#include <math.h>

typedef __attribute__((ext_vector_type(8))) short bf16x8;
typedef __attribute__((ext_vector_type(4))) float f32x4;

__device__ __forceinline__ unsigned short f2b(float f) {
  unsigned u = __float_as_uint(f);
  unsigned r = (u + 0x7FFF + ((u >> 16) & 1)) >> 16;
  return (unsigned short)r;
}

__device__ __forceinline__ void async16(const void* g, void* l) {
  __builtin_amdgcn_global_load_lds(
      (const __attribute__((address_space(1))) unsigned int*)(g),
      (__attribute__((address_space(3))) unsigned int*)(l), 16, 0, 0);
}

// ---------------------------------------------------------------------------
// fp32 -> bf16 (RNE) conversion, 4 elems/thread
// ---------------------------------------------------------------------------
__global__ __launch_bounds__(256) void cvt_bf16(
    const float* __restrict__ s, unsigned short* __restrict__ d, int n4)
{
  int i = blockIdx.x * 256 + threadIdx.x;
  if (i < n4) {
    float4 v = ((const float4*)s)[i];
    ushort4 o;
    o.x = f2b(v.x); o.y = f2b(v.y); o.z = f2b(v.z); o.w = f2b(v.w);
    ((ushort4*)d)[i] = o;
  }
}

// ---------------------------------------------------------------------------
// bf16 MFMA GEMM (m97 structure): C[M,N] = A[M,K] @ B[N,K]^T + bias, fp32 out.
// 128x128 tile, BK=32, 256 threads (4 waves, 2x2 of 64x64 each).
// M%128==0, N%128==0, K%32==0.
// ---------------------------------------------------------------------------
__global__ __launch_bounds__(256) void gemm_mfma_bt(
    const unsigned short* __restrict__ A, const unsigned short* __restrict__ B,
    const float* __restrict__ bias, float* __restrict__ C,
    int M, int N, int K)
{
  __shared__ __align__(16) unsigned short As[128 * 32];
  __shared__ __align__(16) unsigned short Bs[128 * 32];
  const int tid = threadIdx.x;
  const int w = tid >> 6, lane = tid & 63;
  const int wr = (w >> 1) * 64, wc = (w & 1) * 64;
  const int row0 = blockIdx.y * 128, col0 = blockIdx.x * 128;

  f32x4 acc[4][4];
  #pragma unroll
  for (int i = 0; i < 4; ++i)
    #pragma unroll
    for (int j = 0; j < 4; ++j)
      acc[i][j] = (f32x4){0.f, 0.f, 0.f, 0.f};

  // staging: wave w covers rows [w*32, w*32+32); lane l -> row w*32+(l>>2),
  // col (l&3)*8 elems; LDS flat index = w*1024 + lane*8 (matches HW lane*16B).
  const int srow = w * 32 + (lane >> 2);
  const int scol = (lane & 3) * 8;
  const unsigned short* gA0 = A + (size_t)(row0 + srow) * K + scol;
  const unsigned short* gA1 = gA0 + (size_t)16 * K;
  const unsigned short* gB0 = B + (size_t)(col0 + srow) * K + scol;
  const unsigned short* gB1 = gB0 + (size_t)16 * K;
  unsigned short* lA0 = As + w * 1024;
  unsigned short* lA1 = As + w * 1024 + 512;
  unsigned short* lB0 = Bs + w * 1024;
  unsigned short* lB1 = Bs + w * 1024 + 512;

  const int m16 = lane & 15;          // row within 16-tile
  const int q8  = (lane >> 4) * 8;    // k offset of this quad

  for (int k0 = 0; k0 < K; k0 += 32) {
    async16(gA0, lA0);
    async16(gA1, lA1);
    async16(gB0, lB0);
    async16(gB1, lB1);
    gA0 += 32; gA1 += 32; gB0 += 32; gB1 += 32;
    __syncthreads();
    bf16x8 af[4], bfr[4];
    #pragma unroll
    for (int i = 0; i < 4; ++i) {
      af[i]  = *(const bf16x8*)(As + (wr + i * 16 + m16) * 32 + q8);
      bfr[i] = *(const bf16x8*)(Bs + (wc + i * 16 + m16) * 32 + q8);
    }
    #pragma unroll
    for (int i = 0; i < 4; ++i)
      #pragma unroll
      for (int j = 0; j < 4; ++j)
        acc[i][j] = __builtin_amdgcn_mfma_f32_16x16x32_bf16(af[i], bfr[j], acc[i][j], 0, 0, 0);
    __syncthreads();
  }

  // C/D layout: col = lane&15, row = (lane>>4)*4 + reg
  #pragma unroll
  for (int j = 0; j < 4; ++j) {
    const int c_ = col0 + wc + j * 16 + (lane & 15);
    const float bv = bias ? bias[c_] : 0.f;
    #pragma unroll
    for (int i = 0; i < 4; ++i) {
      const int r_ = row0 + wr + i * 16 + (lane >> 4) * 4;
      #pragma unroll
      for (int t4 = 0; t4 < 4; ++t4)
        C[(size_t)(r_ + t4) * N + c_] = acc[i][j][t4] + bv;
    }
  }
}

// ---------------------------------------------------------------------------
// Tiled fp32 GEMM (for the small low-rank projections).
// TRANSB=1: A @ B^T (B is N x K);  TRANSB=0: A @ B (B is K x N).
// ---------------------------------------------------------------------------
#define GBK 16
#define LDT 68

template<int TRANSB, int ACT>
__global__ __launch_bounds__(256) void gemm_f32(
    const float* __restrict__ A, const float* __restrict__ B,
    const float* __restrict__ bias, float* __restrict__ C,
    int M, int N, int K)
{
  __shared__ float As[GBK * LDT];
  __shared__ float Bs[GBK * LDT];
  const int tid = threadIdx.x;
  const int bx = blockIdx.x, by = blockIdx.y;
  const int tx = tid & 15, ty = tid >> 4;
  const int row0 = by * 64, col0 = bx * 64;
  float acc[4][4] = {{0.f,0.f,0.f,0.f},{0.f,0.f,0.f,0.f},
                     {0.f,0.f,0.f,0.f},{0.f,0.f,0.f,0.f}};
  const int lm  = tid >> 2;
  const int lk4 = (tid & 3) << 2;
  const int lkr = tid >> 4;
  const int ln4 = (tid & 15) << 2;

  for (int k0 = 0; k0 < K; k0 += GBK) {
    float4 av = *(const float4*)(A + (size_t)(row0 + lm) * K + k0 + lk4);
    As[(lk4+0)*LDT + lm] = av.x;
    As[(lk4+1)*LDT + lm] = av.y;
    As[(lk4+2)*LDT + lm] = av.z;
    As[(lk4+3)*LDT + lm] = av.w;
    if constexpr (TRANSB) {
      float4 bv = make_float4(0.f,0.f,0.f,0.f);
      if (col0 + lm < N)
        bv = *(const float4*)(B + (size_t)(col0 + lm) * K + k0 + lk4);
      Bs[(lk4+0)*LDT + lm] = bv.x;
      Bs[(lk4+1)*LDT + lm] = bv.y;
      Bs[(lk4+2)*LDT + lm] = bv.z;
      Bs[(lk4+3)*LDT + lm] = bv.w;
    } else {
      float4 bv = make_float4(0.f,0.f,0.f,0.f);
      if (col0 + ln4 < N)
        bv = *(const float4*)(B + (size_t)(k0 + lkr) * N + col0 + ln4);
      *(float4*)(&Bs[lkr*LDT + ln4]) = bv;
    }
    __syncthreads();
    #pragma unroll
    for (int k = 0; k < GBK; ++k) {
      float4 a4 = *(const float4*)(&As[k*LDT + ty*4]);
      float4 b4 = *(const float4*)(&Bs[k*LDT + tx*4]);
      float am[4] = {a4.x, a4.y, a4.z, a4.w};
      float bm[4] = {b4.x, b4.y, b4.z, b4.w};
      #pragma unroll
      for (int i = 0; i < 4; ++i)
        #pragma unroll
        for (int j = 0; j < 4; ++j)
          acc[i][j] = fmaf(am[i], bm[j], acc[i][j]);
    }
    __syncthreads();
  }
  #pragma unroll
  for (int i = 0; i < 4; ++i) {
    const int r = row0 + ty*4 + i;
    #pragma unroll
    for (int j = 0; j < 4; ++j) {
      const int c = col0 + tx*4 + j;
      if (c < N) {
        float v = acc[i][j];
        if (bias) v += bias[c];
        if (ACT == 1) v = tanhf(v);
        C[(size_t)r * N + c] = v;
      }
    }
  }
}

// ---------------------------------------------------------------------------
// Elementwise prep (unchanged from round 0).
// ---------------------------------------------------------------------------
__global__ __launch_bounds__(256) void prep_kernel(
    const float* __restrict__ k_buf, const float* __restrict__ v_buf,
    float* wt_decay, const float* __restrict__ at, float* vt_vf,
    const float* __restrict__ v_first,
    const float* __restrict__ w0, const float* __restrict__ a0,
    const float* __restrict__ v0, const float* __restrict__ k_k,
    const float* __restrict__ k_a,
    float* __restrict__ kf, float* __restrict__ aaq, float* __restrict__ bbq)
{
  const int row = blockIdx.x;
  const int tid = threadIdx.x;
  const int c0 = tid << 3;
  const int h = tid >> 3;
  const int kvoff = (h >> 2) << 6;
  const size_t base = (size_t)row * 2048;
  const size_t kvrow = (size_t)row * 512;
  float kr[8], kkr[8];
  float ss = 0.f;
  #pragma unroll
  for (int e = 0; e < 8; ++e) {
    const int c = c0 + e;
    const float kv = k_buf[kvrow + kvoff + (c & 63)];
    kr[e] = kv;
    const float t = kv * k_k[c];
    kkr[e] = t;
    ss = fmaf(t, t, ss);
  }
  ss += __shfl_xor(ss, 1);
  ss += __shfl_xor(ss, 2);
  ss += __shfl_xor(ss, 4);
  const float inv = 1.f / fmaxf(sqrtf(ss), 1e-12f);
  #pragma unroll
  for (int e = 0; e < 8; ++e) {
    const int c = c0 + e;
    const size_t idx = base + c;
    const float kk = kkr[e] * inv;
    const float a = 1.f / (1.f + expf(-(a0[c] + at[idx])));
    const float u = w0[c] + wt_decay[idx];
    const float sig_u = 1.f / (1.f + expf(-u));
    wt_decay[idx] = expf(-0.5488116360940264f * sig_u);
    kf[idx] = kr[e] * fmaf(a - 1.f, k_a[c], 1.f);
    const float vr = v_buf[kvrow + kvoff + (c & 63)];
    const float sv = 1.f / (1.f + expf(-(v0[c] + vt_vf[idx])));
    vt_vf[idx] = vr + (v_first[idx] - vr) * sv;
    aaq[idx] = -kk;
    bbq[idx] = kk * a;
  }
}

// ---------------------------------------------------------------------------
// RWKV-7 scan, 8 waves per (b,h): lane=row, wave w owns cols [8w, 8w+8).
// Quad-buffered LDS vec staging, distance-2 register prefetch, double-
// buffered sa/y partials, one barrier per step.
// ---------------------------------------------------------------------------
__global__ __launch_bounds__(512) void scan_kernel(
    const float* __restrict__ rB, const float* __restrict__ dB,
    const float* __restrict__ kB, const float* __restrict__ vB,
    const float* __restrict__ aB, const float* __restrict__ bB,
    const float* __restrict__ state, float* __restrict__ y)
{
  const int bh = blockIdx.x;
  const int b = bh >> 5, h = bh & 31;
  const int tid = threadIdx.x;
  const int w = tid >> 6, lane = tid & 63;
  const int cb = w << 3;

  __shared__ __align__(16) float vecs[4][384];  // [a|d|b|k|r|v] x 64 each
  __shared__ float P[2][8][64];                 // sa partials [parity][wave][row]
  __shared__ float Yp[2][8][64];                // y  partials

  float S[8];
  {
    const float* sp = state + (size_t)bh * 4096 + (size_t)lane * 64 + cb;
    #pragma unroll
    for (int c = 0; c < 8; ++c) S[c] = sp[c];
  }
  const size_t base0 = ((size_t)b * 1024) * 2048 + (size_t)h * 64;

  const float* p0 = nullptr;
  if (tid < 384) {
    const int ai = tid >> 6;
    const float* s_ = (ai == 0) ? aB : (ai == 1) ? dB : (ai == 2) ? bB
                    : (ai == 3) ? kB : (ai == 4) ? rB : vB;
    p0 = s_ + base0 + (tid & 63);
  }
  float g0 = 0.f, g1 = 0.f;
  if (tid < 384) {
    float t0 = p0[0];       vecs[0][tid] = t0;
    float t1 = p0[2048];    vecs[1][tid] = t1;
    g0 = p0[2 * 2048];
    g1 = p0[3 * 2048];
  }
  __syncthreads();

  for (int t = 0; t < 1024; ++t) {
    const int pb = t & 1;
    const float* vp = &vecs[t & 3][0];
    // sa partial over this wave's 8 columns
    const float4 a0v = *(const float4*)(vp + cb);
    const float4 a1v = *(const float4*)(vp + cb + 4);
    float q0 = fmaf(S[1], a0v.y, S[0] * a0v.x);
    float q1 = fmaf(S[3], a0v.w, S[2] * a0v.z);
    float q2 = fmaf(S[5], a1v.y, S[4] * a1v.x);
    float q3 = fmaf(S[7], a1v.w, S[6] * a1v.z);
    P[pb][w][lane] = (q0 + q1) + (q2 + q3);
    __syncthreads();
    // combine sa (all waves)
    float sa;
    {
      float u0 = P[pb][0][lane] + P[pb][1][lane];
      float u1 = P[pb][2][lane] + P[pb][3][lane];
      float u2 = P[pb][4][lane] + P[pb][5][lane];
      float u3 = P[pb][6][lane] + P[pb][7][lane];
      sa = (u0 + u1) + (u2 + u3);
    }
    // emit y(t-1)
    if (w == 0 && t > 0) {
      const int pm = pb ^ 1;
      float u0 = Yp[pm][0][lane] + Yp[pm][1][lane];
      float u1 = Yp[pm][2][lane] + Yp[pm][3][lane];
      float u2 = Yp[pm][4][lane] + Yp[pm][5][lane];
      float u3 = Yp[pm][6][lane] + Yp[pm][7][lane];
      y[base0 + (size_t)(t - 1) * 2048 + lane] = (u0 + u1) + (u2 + u3);
    }
    // update S and y partial
    const float vi = vp[320 + lane];
    const float4 d0v = *(const float4*)(vp + 64 + cb);
    const float4 d1v = *(const float4*)(vp + 64 + cb + 4);
    const float4 b0v = *(const float4*)(vp + 128 + cb);
    const float4 b1v = *(const float4*)(vp + 128 + cb + 4);
    const float4 k0v = *(const float4*)(vp + 192 + cb);
    const float4 k1v = *(const float4*)(vp + 192 + cb + 4);
    const float4 r0v = *(const float4*)(vp + 256 + cb);
    const float4 r1v = *(const float4*)(vp + 256 + cb + 4);
    float ya, yb;
    S[0] = fmaf(S[0], d0v.x, fmaf(sa, b0v.x, vi * k0v.x)); ya = S[0] * r0v.x;
    S[1] = fmaf(S[1], d0v.y, fmaf(sa, b0v.y, vi * k0v.y)); ya = fmaf(S[1], r0v.y, ya);
    S[2] = fmaf(S[2], d0v.z, fmaf(sa, b0v.z, vi * k0v.z)); ya = fmaf(S[2], r0v.z, ya);
    S[3] = fmaf(S[3], d0v.w, fmaf(sa, b0v.w, vi * k0v.w)); ya = fmaf(S[3], r0v.w, ya);
    S[4] = fmaf(S[4], d1v.x, fmaf(sa, b1v.x, vi * k1v.x)); yb = S[4] * r1v.x;
    S[5] = fmaf(S[5], d1v.y, fmaf(sa, b1v.y, vi * k1v.y)); yb = fmaf(S[5], r1v.y, yb);
    S[6] = fmaf(S[6], d1v.z, fmaf(sa, b1v.z, vi * k1v.z)); yb = fmaf(S[6], r1v.z, yb);
    S[7] = fmaf(S[7], d1v.w, fmaf(sa, b1v.w, vi * k1v.w)); yb = fmaf(S[7], r1v.w, yb);
    Yp[pb][w][lane] = ya + yb;
    // stage t+2 into LDS; issue load for t+4
    if (tid < 384) {
      vecs[(t + 2) & 3][tid] = g0;
      g0 = g1;
      const int tn = (t + 4 < 1024) ? (t + 4) : 1023;
      g1 = p0[(size_t)tn * 2048];
    }
  }
  __syncthreads();
  if (w == 0) {
    float u0 = Yp[1][0][lane] + Yp[1][1][lane];
    float u1 = Yp[1][2][lane] + Yp[1][3][lane];
    float u2 = Yp[1][4][lane] + Yp[1][5][lane];
    float u3 = Yp[1][6][lane] + Yp[1][7][lane];
    y[base0 + (size_t)1023 * 2048 + lane] = (u0 + u1) + (u2 + u3);
  }
}

// ---------------------------------------------------------------------------
// GroupNorm + bonus; writes xx in bf16 for the O GEMM.
// ---------------------------------------------------------------------------
__global__ __launch_bounds__(256) void gnorm_kernel(
    const float* __restrict__ y, const float* __restrict__ rB,
    const float* __restrict__ kf, const float* __restrict__ vf,
    const float* __restrict__ r_k, const float* __restrict__ ln_w,
    const float* __restrict__ ln_b, unsigned short* __restrict__ xxb)
{
  const int bh = blockIdx.x;
  const int b = bh >> 5, h = bh & 31;
  const int tid = threadIdx.x;
  const size_t base = ((size_t)b * 1024) * 2048 + (size_t)h * 64;
  float s = 0.f, ss = 0.f;
  for (int i = tid; i < 65536; i += 256) {
    const int t = i >> 6, n = i & 63;
    const float v = y[base + (size_t)t * 2048 + n];
    s += v;
    ss = fmaf(v, v, ss);
  }
  #pragma unroll
  for (int o = 1; o < 64; o <<= 1) {
    s  += __shfl_xor(s, o);
    ss += __shfl_xor(ss, o);
  }
  __shared__ float red[8];
  const int wid = tid >> 6;
  if ((tid & 63) == 0) { red[wid] = s; red[4 + wid] = ss; }
  __syncthreads();
  const float st  = red[0] + red[1] + red[2] + red[3];
  const float sst = red[4] + red[5] + red[6] + red[7];
  const float mean = st * (1.f / 65536.f);
  const float var  = sst * (1.f / 65536.f) - mean * mean;
  const float rstd = rsqrtf(var + 0.00064f);
  const int n0 = tid & 63;
  const float lw  = ln_w[h * 64 + n0];
  const float lb  = ln_b[h * 64 + n0];
  const float rkv = r_k [h * 64 + n0];
  for (int i = tid; i < 65536; i += 256) {
    const int t = i >> 6;
    const size_t idx = base + (size_t)t * 2048 + n0;
    float p = rB[idx] * kf[idx] * rkv;
    #pragma unroll
    for (int o = 1; o < 64; o <<= 1) p += __shfl_xor(p, o);
    const float yn = (y[idx] - mean) * rstd;
    xxb[idx] = f2b(fmaf(yn, lw, lb) + p * vf[idx]);
  }
}

// ---------------------------------------------------------------------------
extern "C" void kernel_launch(void* const* d_in, const int* in_sizes, int n_in,
                              void* d_out, int out_size, void* d_ws, size_t ws_size,
                              hipStream_t stream) {
  const float* x       = (const float*)d_in[0];
  const float* v_first = (const float*)d_in[1];
  const float* state   = (const float*)d_in[2];
  const float* Rw      = (const float*)d_in[3];
  const float* R_bias  = (const float*)d_in[4];
  const float* Kw      = (const float*)d_in[5];
  const float* K_bias  = (const float*)d_in[6];
  const float* Vw      = (const float*)d_in[7];
  const float* V_bias  = (const float*)d_in[8];
  const float* Ow      = (const float*)d_in[9];
  const float* O_bias  = (const float*)d_in[10];
  const float* w0      = (const float*)d_in[11];
  const float* w1      = (const float*)d_in[12];
  const float* w2      = (const float*)d_in[13];
  const float* a0      = (const float*)d_in[14];
  const float* a1      = (const float*)d_in[15];
  const float* a2      = (const float*)d_in[16];
  const float* v0      = (const float*)d_in[17];
  const float* v1      = (const float*)d_in[18];
  const float* v2      = (const float*)d_in[19];
  const float* k_k     = (const float*)d_in[20];
  const float* k_a     = (const float*)d_in[21];
  const float* r_k     = (const float*)d_in[22];
  const float* ln_w    = (const float*)d_in[23];
  const float* ln_b    = (const float*)d_in[24];

  float* ws = (float*)d_ws;
  float* r_buf = ws;                    // 8388608
  float* k_buf = r_buf + 8388608;       // 2097152
  float* v_buf = k_buf + 2097152;       // 2097152
  float* hw    = v_buf + 2097152;       // 262144
  float* ha    = hw    + 262144;        // 262144
  float* hv    = ha    + 262144;        // 131072
  float* wt    = hv    + 131072;        // 8388608 (w_raw -> decay in place)
  float* at    = wt    + 8388608;       // 8388608 (a-gate pre-act -> y after scan)
  float* vt    = at    + 8388608;       // 8388608 (v-gate pre-act -> v_final in place)
  float* kf    = vt    + 8388608;       // 8388608
  float* aaq   = kf    + 8388608;       // 8388608
  float* bbq   = aaq   + 8388608;       // 8388608
  // bf16 aliases into regions that are dead at time of use:
  unsigned short* xb  = (unsigned short*)bbq;               // x bf16 (dead before prep writes bbq)
  unsigned short* Rb  = (unsigned short*)kf;                // R bf16 (dead before prep writes kf)
  unsigned short* Kb  = (unsigned short*)aaq;               // K bf16
  unsigned short* Vb  = (unsigned short*)(aaq + 524288);    // V bf16
  unsigned short* Ob  = (unsigned short*)wt;                // O bf16 (after scan; wt dead)
  unsigned short* xxb = (unsigned short*)aaq;               // xx bf16 (after scan; aaq dead)

  dim3 blk(256);
  // ---- bf16 conversions ----
  cvt_bf16<<<8192, blk, 0, stream>>>(x,  xb, 2097152);
  cvt_bf16<<<4096, blk, 0, stream>>>(Rw, Rb, 1048576);
  cvt_bf16<<<1024, blk, 0, stream>>>(Kw, Kb, 262144);
  cvt_bf16<<<1024, blk, 0, stream>>>(Vw, Vb, 262144);
  // ---- big projections (bf16 MFMA) ----
  gemm_mfma_bt<<<dim3(16,32), blk, 0, stream>>>(xb, Rb, R_bias, r_buf, 4096, 2048, 2048);
  gemm_mfma_bt<<<dim3( 4,32), blk, 0, stream>>>(xb, Kb, K_bias, k_buf, 4096,  512, 2048);
  gemm_mfma_bt<<<dim3( 4,32), blk, 0, stream>>>(xb, Vb, V_bias, v_buf, 4096,  512, 2048);
  // ---- low-rank paths (fp32) ----
  gemm_f32<0,1><<<dim3( 1,64), blk, 0, stream>>>(x,  w1, nullptr, hw, 4096,   64, 2048);
  gemm_f32<0,0><<<dim3( 1,64), blk, 0, stream>>>(x,  a1, nullptr, ha, 4096,   64, 2048);
  gemm_f32<0,0><<<dim3( 1,64), blk, 0, stream>>>(x,  v1, nullptr, hv, 4096,   32, 2048);
  gemm_f32<0,0><<<dim3(32,64), blk, 0, stream>>>(hw, w2, nullptr, wt, 4096, 2048,   64);
  gemm_f32<0,0><<<dim3(32,64), blk, 0, stream>>>(ha, a2, nullptr, at, 4096, 2048,   64);
  gemm_f32<0,0><<<dim3(32,64), blk, 0, stream>>>(hv, v2, nullptr, vt, 4096, 2048,   32);
  // ---- elementwise prep ----
  prep_kernel<<<4096, blk, 0, stream>>>(k_buf, v_buf, wt, at, vt, v_first,
                                        w0, a0, v0, k_k, k_a, kf, aaq, bbq);
  // ---- recurrent scan (y reuses `at`) ----
  float* ybuf = at;
  scan_kernel<<<128, 512, 0, stream>>>(r_buf, wt, kf, vt, aaq, bbq, state, ybuf);
  // ---- group norm + bonus -> bf16 xx ----
  gnorm_kernel<<<128, blk, 0, stream>>>(ybuf, r_buf, kf, vt, r_k, ln_w, ln_b, xxb);
  // ---- output projection ----
  cvt_bf16<<<4096, blk, 0, stream>>>(Ow, Ob, 1048576);
  gemm_mfma_bt<<<dim3(16,32), blk, 0, stream>>>(xxb, Ob, O_bias, (float*)d_out,
                                                4096, 2048, 2048);
}

// Round 3
// 1353.340 us; speedup vs baseline: 3.2014x; 1.5626x over previous
//
#include <hip/hip_runtime.h>
#include <hip/hip_bf16.h>
#include <math.h>

typedef __attribute__((ext_vector_type(8))) short bf16x8;
typedef __attribute__((ext_vector_type(4))) float f32x4;

__device__ __forceinline__ unsigned short f2b(float f) {
  unsigned u = __float_as_uint(f);
  unsigned r = (u + 0x7FFF + ((u >> 16) & 1)) >> 16;
  return (unsigned short)r;
}

__device__ __forceinline__ void async16(const void* g, void* l) {
  __builtin_amdgcn_global_load_lds(
      (const __attribute__((address_space(1))) unsigned int*)(g),
      (__attribute__((address_space(3))) unsigned int*)(l), 16, 0, 0);
}

// ---------------------------------------------------------------------------
// fp32 -> bf16 converts: x,R,K,V fused in one launch; plain one for O.
// ---------------------------------------------------------------------------
__global__ __launch_bounds__(256) void cvt4_kernel(
    const float* __restrict__ x, const float* __restrict__ R,
    const float* __restrict__ K, const float* __restrict__ V,
    unsigned short* __restrict__ xb, unsigned short* __restrict__ Rb,
    unsigned short* __restrict__ Kb, unsigned short* __restrict__ Vb)
{
  const int bid = blockIdx.x;
  const float* s; unsigned short* d; int i;
  if (bid < 8192)       { s = x; d = xb; i = bid * 256 + threadIdx.x; }
  else if (bid < 12288) { s = R; d = Rb; i = (bid - 8192) * 256 + threadIdx.x; }
  else if (bid < 13312) { s = K; d = Kb; i = (bid - 12288) * 256 + threadIdx.x; }
  else                  { s = V; d = Vb; i = (bid - 13312) * 256 + threadIdx.x; }
  float4 v = ((const float4*)s)[i];
  ushort4 o;
  o.x = f2b(v.x); o.y = f2b(v.y); o.z = f2b(v.z); o.w = f2b(v.w);
  ((ushort4*)d)[i] = o;
}

__global__ __launch_bounds__(256) void cvt_bf16(
    const float* __restrict__ s, unsigned short* __restrict__ d, int n4)
{
  int i = blockIdx.x * 256 + threadIdx.x;
  if (i < n4) {
    float4 v = ((const float4*)s)[i];
    ushort4 o;
    o.x = f2b(v.x); o.y = f2b(v.y); o.z = f2b(v.z); o.w = f2b(v.w);
    ((ushort4*)d)[i] = o;
  }
}

// ---------------------------------------------------------------------------
// Transposed convert: out[n*ors + k] = bf16(in[k*Nd + n]), k<Kd, n<Nd.
// ---------------------------------------------------------------------------
__global__ __launch_bounds__(256) void tcvt_kernel(
    const float* __restrict__ in, unsigned short* __restrict__ out,
    int Kd, int Nd, int ors)
{
  __shared__ unsigned short tile[64][65];
  const int tx = threadIdx.x & 63, ty = threadIdx.x >> 6;
  const int n0 = blockIdx.x * 64, k0 = blockIdx.y * 64;
  #pragma unroll
  for (int j = 0; j < 16; ++j) {
    const int k = k0 + j * 4 + ty;
    const int n = n0 + tx;
    unsigned short v = 0;
    if (k < Kd && n < Nd) v = f2b(in[(size_t)k * Nd + n]);
    tile[j * 4 + ty][tx] = v;
  }
  __syncthreads();
  #pragma unroll
  for (int j = 0; j < 16; ++j) {
    const int n = n0 + j * 4 + ty;
    const int k = k0 + tx;
    if (n < Nd && k < Kd) out[(size_t)n * ors + k] = tile[tx][j * 4 + ty];
  }
}

// ---------------------------------------------------------------------------
// bf16 MFMA GEMM: C[M,N] = A[M,K] @ B[N,K]^T (+bias). 128x128 tile, BK=32.
// lda/ldb/ldc in elements. M%128==0, K%32==0; N guarded (B rows clamped).
// OUTBF16: 1 -> bf16 output. ACT: 2 -> tanh on global cols < 64.
// ---------------------------------------------------------------------------
template<int OUTBF16, int ACT>
__global__ __launch_bounds__(256) void gemm_mfma(
    const unsigned short* __restrict__ A, int lda,
    const unsigned short* __restrict__ B, int ldb,
    const float* __restrict__ bias, void* __restrict__ Cv, int ldc,
    int M, int N, int K)
{
  __shared__ __align__(16) unsigned short As[128 * 32];
  __shared__ __align__(16) unsigned short Bs[128 * 32];
  const int tid = threadIdx.x;
  const int w = tid >> 6, lane = tid & 63;
  const int wr = (w >> 1) * 64, wc = (w & 1) * 64;
  const int row0 = blockIdx.y * 128, col0 = blockIdx.x * 128;

  f32x4 acc[4][4];
  #pragma unroll
  for (int i = 0; i < 4; ++i)
    #pragma unroll
    for (int j = 0; j < 4; ++j)
      acc[i][j] = (f32x4){0.f, 0.f, 0.f, 0.f};

  const int srow = w * 32 + (lane >> 2);
  const int scol = (lane & 3) * 8;
  const int brow0 = (col0 + srow < N) ? (col0 + srow) : 0;
  const int brow1 = (col0 + srow + 16 < N) ? (col0 + srow + 16) : 0;
  const unsigned short* gA0 = A + (size_t)(row0 + srow) * lda + scol;
  const unsigned short* gA1 = gA0 + (size_t)16 * lda;
  const unsigned short* gB0 = B + (size_t)brow0 * ldb + scol;
  const unsigned short* gB1 = B + (size_t)brow1 * ldb + scol;
  unsigned short* lA0 = As + w * 1024;
  unsigned short* lA1 = As + w * 1024 + 512;
  unsigned short* lB0 = Bs + w * 1024;
  unsigned short* lB1 = Bs + w * 1024 + 512;

  const int m16 = lane & 15;
  const int q8  = (lane >> 4) * 8;

  for (int k0 = 0; k0 < K; k0 += 32) {
    async16(gA0, lA0);
    async16(gA1, lA1);
    async16(gB0, lB0);
    async16(gB1, lB1);
    gA0 += 32; gA1 += 32; gB0 += 32; gB1 += 32;
    __syncthreads();
    bf16x8 af[4], bfr[4];
    #pragma unroll
    for (int i = 0; i < 4; ++i) {
      af[i]  = *(const bf16x8*)(As + (wr + i * 16 + m16) * 32 + q8);
      bfr[i] = *(const bf16x8*)(Bs + (wc + i * 16 + m16) * 32 + q8);
    }
    #pragma unroll
    for (int i = 0; i < 4; ++i)
      #pragma unroll
      for (int j = 0; j < 4; ++j)
        acc[i][j] = __builtin_amdgcn_mfma_f32_16x16x32_bf16(af[i], bfr[j], acc[i][j], 0, 0, 0);
    __syncthreads();
  }

  // C/D layout: col = lane&15, row = (lane>>4)*4 + reg
  #pragma unroll
  for (int j = 0; j < 4; ++j) {
    const int c_ = col0 + wc + j * 16 + (lane & 15);
    if (c_ < N) {
      const float bv = bias ? bias[c_] : 0.f;
      #pragma unroll
      for (int i = 0; i < 4; ++i) {
        const int r_ = row0 + wr + i * 16 + (lane >> 4) * 4;
        #pragma unroll
        for (int t4 = 0; t4 < 4; ++t4) {
          float v = acc[i][j][t4] + bv;
          if (ACT == 2 && c_ < 64) v = tanhf(v);
          if (OUTBF16)
            ((unsigned short*)Cv)[(size_t)(r_ + t4) * ldc + c_] = f2b(v);
          else
            ((float*)Cv)[(size_t)(r_ + t4) * ldc + c_] = v;
        }
      }
    }
  }
}

// ---------------------------------------------------------------------------
// Elementwise prep (unchanged).
// ---------------------------------------------------------------------------
__global__ __launch_bounds__(256) void prep_kernel(
    const float* __restrict__ k_buf, const float* __restrict__ v_buf,
    float* wt_decay, const float* __restrict__ at, float* vt_vf,
    const float* __restrict__ v_first,
    const float* __restrict__ w0, const float* __restrict__ a0,
    const float* __restrict__ v0, const float* __restrict__ k_k,
    const float* __restrict__ k_a,
    float* __restrict__ kf, float* __restrict__ aaq, float* __restrict__ bbq)
{
  const int row = blockIdx.x;
  const int tid = threadIdx.x;
  const int c0 = tid << 3;
  const int h = tid >> 3;
  const int kvoff = (h >> 2) << 6;
  const size_t base = (size_t)row * 2048;
  const size_t kvrow = (size_t)row * 512;
  float kr[8], kkr[8];
  float ss = 0.f;
  #pragma unroll
  for (int e = 0; e < 8; ++e) {
    const int c = c0 + e;
    const float kv = k_buf[kvrow + kvoff + (c & 63)];
    kr[e] = kv;
    const float t = kv * k_k[c];
    kkr[e] = t;
    ss = fmaf(t, t, ss);
  }
  ss += __shfl_xor(ss, 1);
  ss += __shfl_xor(ss, 2);
  ss += __shfl_xor(ss, 4);
  const float inv = 1.f / fmaxf(sqrtf(ss), 1e-12f);
  #pragma unroll
  for (int e = 0; e < 8; ++e) {
    const int c = c0 + e;
    const size_t idx = base + c;
    const float kk = kkr[e] * inv;
    const float a = 1.f / (1.f + expf(-(a0[c] + at[idx])));
    const float u = w0[c] + wt_decay[idx];
    const float sig_u = 1.f / (1.f + expf(-u));
    wt_decay[idx] = expf(-0.5488116360940264f * sig_u);
    kf[idx] = kr[e] * fmaf(a - 1.f, k_a[c], 1.f);
    const float vr = v_buf[kvrow + kvoff + (c & 63)];
    const float sv = 1.f / (1.f + expf(-(v0[c] + vt_vf[idx])));
    vt_vf[idx] = vr + (v_first[idx] - vr) * sv;
    aaq[idx] = -kk;
    bbq[idx] = kk * a;
  }
}

// ---------------------------------------------------------------------------
// RWKV-7 scan, 8 waves per (b,h); burst global I/O every 8 steps so that
// 7 of 8 barriers have zero outstanding vmem (no vmcnt(0) drain stall).
// ---------------------------------------------------------------------------
__global__ __launch_bounds__(512) void scan_kernel(
    const float* __restrict__ rB, const float* __restrict__ dB,
    const float* __restrict__ kB, const float* __restrict__ vB,
    const float* __restrict__ aB, const float* __restrict__ bB,
    const float* __restrict__ state, float* __restrict__ y)
{
  const int bh = blockIdx.x;
  const int b = bh >> 5, h = bh & 31;
  const int tid = threadIdx.x;
  const int w = tid >> 6, lane = tid & 63;
  const int cb = w << 3;

  __shared__ __align__(16) float vecs[16][384];  // [a|d|b|k|r|v] x 64 each
  __shared__ float P[2][8][64];
  __shared__ float Yp[2][8][64];

  float S[8];
  {
    const float* sp = state + (size_t)bh * 4096 + (size_t)lane * 64 + cb;
    #pragma unroll
    for (int c = 0; c < 8; ++c) S[c] = sp[c];
  }
  const size_t base0 = ((size_t)b * 1024) * 2048 + (size_t)h * 64;

  const float* p0 = nullptr;
  if (tid < 384) {
    const int ai = tid >> 6;
    const float* s_ = (ai == 0) ? aB : (ai == 1) ? dB : (ai == 2) ? bB
                    : (ai == 3) ? kB : (ai == 4) ? rB : vB;
    p0 = s_ + base0 + (tid & 63);
  }
  float g[8];
  if (tid < 384) {
    #pragma unroll
    for (int j = 0; j < 8; ++j) vecs[j][tid] = p0[(size_t)j * 2048];
    #pragma unroll
    for (int j = 0; j < 8; ++j) g[j] = p0[(size_t)(8 + j) * 2048];
  }
  float yb[8];
  __syncthreads();

  #pragma unroll 8
  for (int t = 0; t < 1024; ++t) {
    const int pb = t & 1;
    const float* vp = &vecs[t & 15][0];
    // sa partial over this wave's 8 columns
    const float4 a0v = *(const float4*)(vp + cb);
    const float4 a1v = *(const float4*)(vp + cb + 4);
    float q0 = fmaf(S[1], a0v.y, S[0] * a0v.x);
    float q1 = fmaf(S[3], a0v.w, S[2] * a0v.z);
    float q2 = fmaf(S[5], a1v.y, S[4] * a1v.x);
    float q3 = fmaf(S[7], a1v.w, S[6] * a1v.z);
    P[pb][w][lane] = (q0 + q1) + (q2 + q3);
    __syncthreads();
    float sa;
    {
      float u0 = P[pb][0][lane] + P[pb][1][lane];
      float u1 = P[pb][2][lane] + P[pb][3][lane];
      float u2 = P[pb][4][lane] + P[pb][5][lane];
      float u3 = P[pb][6][lane] + P[pb][7][lane];
      sa = (u0 + u1) + (u2 + u3);
    }
    // y(t-1): buffer in regs, burst-store every 8 steps (wave 0)
    if (w == 0 && t > 0) {
      const int pm = pb ^ 1;
      float u0 = Yp[pm][0][lane] + Yp[pm][1][lane];
      float u1 = Yp[pm][2][lane] + Yp[pm][3][lane];
      float u2 = Yp[pm][4][lane] + Yp[pm][5][lane];
      float u3 = Yp[pm][6][lane] + Yp[pm][7][lane];
      yb[(t - 1) & 7] = (u0 + u1) + (u2 + u3);
      if ((t & 7) == 0) {
        #pragma unroll
        for (int j = 0; j < 8; ++j)
          y[base0 + (size_t)(t - 8 + j) * 2048 + lane] = yb[j];
      }
    }
    // update S and y partial
    const float vi = vp[320 + lane];
    const float4 d0v = *(const float4*)(vp + 64 + cb);
    const float4 d1v = *(const float4*)(vp + 64 + cb + 4);
    const float4 b0v = *(const float4*)(vp + 128 + cb);
    const float4 b1v = *(const float4*)(vp + 128 + cb + 4);
    const float4 k0v = *(const float4*)(vp + 192 + cb);
    const float4 k1v = *(const float4*)(vp + 192 + cb + 4);
    const float4 r0v = *(const float4*)(vp + 256 + cb);
    const float4 r1v = *(const float4*)(vp + 256 + cb + 4);
    float ya, yc;
    S[0] = fmaf(S[0], d0v.x, fmaf(sa, b0v.x, vi * k0v.x)); ya = S[0] * r0v.x;
    S[1] = fmaf(S[1], d0v.y, fmaf(sa, b0v.y, vi * k0v.y)); ya = fmaf(S[1], r0v.y, ya);
    S[2] = fmaf(S[2], d0v.z, fmaf(sa, b0v.z, vi * k0v.z)); ya = fmaf(S[2], r0v.z, ya);
    S[3] = fmaf(S[3], d0v.w, fmaf(sa, b0v.w, vi * k0v.w)); ya = fmaf(S[3], r0v.w, ya);
    S[4] = fmaf(S[4], d1v.x, fmaf(sa, b1v.x, vi * k1v.x)); yc = S[4] * r1v.x;
    S[5] = fmaf(S[5], d1v.y, fmaf(sa, b1v.y, vi * k1v.y)); yc = fmaf(S[5], r1v.y, yc);
    S[6] = fmaf(S[6], d1v.z, fmaf(sa, b1v.z, vi * k1v.z)); yc = fmaf(S[6], r1v.z, yc);
    S[7] = fmaf(S[7], d1v.w, fmaf(sa, b1v.w, vi * k1v.w)); yc = fmaf(S[7], r1v.w, yc);
    Yp[pb][w][lane] = ya + yc;
    // burst: stage next 8 steps from regs, load 8 more
    if ((t & 7) == 0 && tid < 384) {
      #pragma unroll
      for (int j = 0; j < 8; ++j) vecs[(t + 8 + j) & 15][tid] = g[j];
      #pragma unroll
      for (int j = 0; j < 8; ++j) {
        int ti = t + 16 + j;
        if (ti > 1023) ti = 1023;
        g[j] = p0[(size_t)ti * 2048];
      }
    }
  }
  __syncthreads();
  if (w == 0) {
    float u0 = Yp[1][0][lane] + Yp[1][1][lane];
    float u1 = Yp[1][2][lane] + Yp[1][3][lane];
    float u2 = Yp[1][4][lane] + Yp[1][5][lane];
    float u3 = Yp[1][6][lane] + Yp[1][7][lane];
    yb[7] = (u0 + u1) + (u2 + u3);
    #pragma unroll
    for (int j = 0; j < 8; ++j)
      y[base0 + (size_t)(1016 + j) * 2048 + lane] = yb[j];
  }
}

// ---------------------------------------------------------------------------
// GroupNorm + bonus; writes xx in bf16.
// ---------------------------------------------------------------------------
__global__ __launch_bounds__(256) void gnorm_kernel(
    const float* __restrict__ y, const float* __restrict__ rB,
    const float* __restrict__ kf, const float* __restrict__ vf,
    const float* __restrict__ r_k, const float* __restrict__ ln_w,
    const float* __restrict__ ln_b, unsigned short* __restrict__ xxb)
{
  const int bh = blockIdx.x;
  const int b = bh >> 5, h = bh & 31;
  const int tid = threadIdx.x;
  const size_t base = ((size_t)b * 1024) * 2048 + (size_t)h * 64;
  float s = 0.f, ss = 0.f;
  for (int i = tid; i < 65536; i += 256) {
    const int t = i >> 6, n = i & 63;
    const float v = y[base + (size_t)t * 2048 + n];
    s += v;
    ss = fmaf(v, v, ss);
  }
  #pragma unroll
  for (int o = 1; o < 64; o <<= 1) {
    s  += __shfl_xor(s, o);
    ss += __shfl_xor(ss, o);
  }
  __shared__ float red[8];
  const int wid = tid >> 6;
  if ((tid & 63) == 0) { red[wid] = s; red[4 + wid] = ss; }
  __syncthreads();
  const float st  = red[0] + red[1] + red[2] + red[3];
  const float sst = red[4] + red[5] + red[6] + red[7];
  const float mean = st * (1.f / 65536.f);
  const float var  = sst * (1.f / 65536.f) - mean * mean;
  const float rstd = rsqrtf(var + 0.00064f);
  const int n0 = tid & 63;
  const float lw  = ln_w[h * 64 + n0];
  const float lb  = ln_b[h * 64 + n0];
  const float rkv = r_k [h * 64 + n0];
  for (int i = tid; i < 65536; i += 256) {
    const int t = i >> 6;
    const size_t idx = base + (size_t)t * 2048 + n0;
    float p = rB[idx] * kf[idx] * rkv;
    #pragma unroll
    for (int o = 1; o < 64; o <<= 1) p += __shfl_xor(p, o);
    const float yn = (y[idx] - mean) * rstd;
    xxb[idx] = f2b(fmaf(yn, lw, lb) + p * vf[idx]);
  }
}

// ---------------------------------------------------------------------------
extern "C" void kernel_launch(void* const* d_in, const int* in_sizes, int n_in,
                              void* d_out, int out_size, void* d_ws, size_t ws_size,
                              hipStream_t stream) {
  const float* x       = (const float*)d_in[0];
  const float* v_first = (const float*)d_in[1];
  const float* state   = (const float*)d_in[2];
  const float* Rw      = (const float*)d_in[3];
  const float* R_bias  = (const float*)d_in[4];
  const float* Kw      = (const float*)d_in[5];
  const float* K_bias  = (const float*)d_in[6];
  const float* Vw      = (const float*)d_in[7];
  const float* V_bias  = (const float*)d_in[8];
  const float* Ow      = (const float*)d_in[9];
  const float* O_bias  = (const float*)d_in[10];
  const float* w0      = (const float*)d_in[11];
  const float* w1      = (const float*)d_in[12];
  const float* w2      = (const float*)d_in[13];
  const float* a0      = (const float*)d_in[14];
  const float* a1      = (const float*)d_in[15];
  const float* a2      = (const float*)d_in[16];
  const float* v0      = (const float*)d_in[17];
  const float* v1      = (const float*)d_in[18];
  const float* v2      = (const float*)d_in[19];
  const float* k_k     = (const float*)d_in[20];
  const float* k_a     = (const float*)d_in[21];
  const float* r_k     = (const float*)d_in[22];
  const float* ln_w    = (const float*)d_in[23];
  const float* ln_b    = (const float*)d_in[24];

  float* ws = (float*)d_ws;
  float* r_buf = ws;                    // 8388608
  float* k_buf = r_buf + 8388608;       // 2097152
  float* v_buf = k_buf + 2097152;       // 2097152
  float* wt    = v_buf + 2097152;       // 8388608 (u -> decay in place)
  float* at    = wt    + 8388608;       // 8388608 (a pre-act -> y after scan)
  float* vt    = at    + 8388608;       // 8388608 (v pre-act -> v_final)
  float* kf    = vt    + 8388608;       // 8388608
  float* aaq   = kf    + 8388608;       // 8388608
  float* bbq   = aaq   + 8388608;       // 8388608
  // bf16 aliases into dead-at-use regions:
  unsigned short* xb   = (unsigned short*)bbq;               // dead before prep
  unsigned short* Rb   = (unsigned short*)kf;                // kf[0..2097152)
  unsigned short* hcat = (unsigned short*)(kf + 2097152);    // 4096x160 bf16
  unsigned short* Bcat = (unsigned short*)(kf + 2424832);    // 160x2048 bf16
  unsigned short* w2t  = (unsigned short*)(kf + 2588672);    // 2048x64
  unsigned short* a2t  = (unsigned short*)(kf + 2654208);    // 2048x64
  unsigned short* v2t  = (unsigned short*)(kf + 2719744);    // 2048x32
  unsigned short* Kb   = (unsigned short*)aaq;
  unsigned short* Vb   = (unsigned short*)(aaq + 524288);
  unsigned short* Ob   = (unsigned short*)wt;                // after scan
  unsigned short* xxb  = (unsigned short*)aaq;               // after scan

  dim3 blk(256);
  // ---- converts ----
  cvt4_kernel<<<14336, blk, 0, stream>>>(x, Rw, Kw, Vw, xb, Rb, Kb, Vb);
  tcvt_kernel<<<dim3(1, 32), blk, 0, stream>>>(w1, Bcat,               2048, 64, 2048);
  tcvt_kernel<<<dim3(1, 32), blk, 0, stream>>>(a1, Bcat + 64 * 2048,   2048, 64, 2048);
  tcvt_kernel<<<dim3(1, 32), blk, 0, stream>>>(v1, Bcat + 128 * 2048,  2048, 32, 2048);
  tcvt_kernel<<<dim3(32, 1), blk, 0, stream>>>(w2, w2t, 64, 2048, 64);
  tcvt_kernel<<<dim3(32, 1), blk, 0, stream>>>(a2, a2t, 64, 2048, 64);
  tcvt_kernel<<<dim3(32, 1), blk, 0, stream>>>(v2, v2t, 32, 2048, 32);
  // ---- low-rank stage 1 (fused, bf16 out, tanh on w-cols) ----
  gemm_mfma<1,2><<<dim3(2, 32), blk, 0, stream>>>(xb, 2048, Bcat, 2048, nullptr,
                                                  hcat, 160, 4096, 160, 2048);
  // ---- big projections ----
  gemm_mfma<0,0><<<dim3(16, 32), blk, 0, stream>>>(xb, 2048, Rb, 2048, R_bias,
                                                   r_buf, 2048, 4096, 2048, 2048);
  gemm_mfma<0,0><<<dim3(4, 32), blk, 0, stream>>>(xb, 2048, Kb, 2048, K_bias,
                                                  k_buf, 512, 4096, 512, 2048);
  gemm_mfma<0,0><<<dim3(4, 32), blk, 0, stream>>>(xb, 2048, Vb, 2048, V_bias,
                                                  v_buf, 512, 4096, 512, 2048);
  // ---- low-rank stage 2 ----
  gemm_mfma<0,0><<<dim3(16, 32), blk, 0, stream>>>(hcat, 160, w2t, 64, nullptr,
                                                   wt, 2048, 4096, 2048, 64);
  gemm_mfma<0,0><<<dim3(16, 32), blk, 0, stream>>>(hcat + 64, 160, a2t, 64, nullptr,
                                                   at, 2048, 4096, 2048, 64);
  gemm_mfma<0,0><<<dim3(16, 32), blk, 0, stream>>>(hcat + 128, 160, v2t, 32, nullptr,
                                                   vt, 2048, 4096, 2048, 32);
  // ---- elementwise prep ----
  prep_kernel<<<4096, blk, 0, stream>>>(k_buf, v_buf, wt, at, vt, v_first,
                                        w0, a0, v0, k_k, k_a, kf, aaq, bbq);
  // ---- recurrent scan (y reuses `at`) ----
  float* ybuf = at;
  scan_kernel<<<128, 512, 0, stream>>>(r_buf, wt, kf, vt, aaq, bbq, state, ybuf);
  // ---- O weight convert (wt dead after scan) ----
  cvt_bf16<<<4096, blk, 0, stream>>>(Ow, Ob, 1048576);
  // ---- group norm + bonus -> bf16 xx ----
  gnorm_kernel<<<128, blk, 0, stream>>>(ybuf, r_buf, kf, vt, r_k, ln_w, ln_b, xxb);
  // ---- output projection ----
  gemm_mfma<0,0><<<dim3(16, 32), blk, 0, stream>>>(xxb, 2048, Ob, 2048, O_bias,
                                                   (float*)d_out, 2048, 4096, 2048, 2048);
}

// Round 4
// 1114.764 us; speedup vs baseline: 3.8865x; 1.2140x over previous
//
#include <hip/hip_runtime.h>
#include <hip/hip_bf16.h>
#include <math.h>

typedef __attribute__((ext_vector_type(8))) short bf16x8;
typedef __attribute__((ext_vector_type(4))) float f32x4;

__device__ __forceinline__ unsigned short f2b(float f) {
  unsigned u = __float_as_uint(f);
  unsigned r = (u + 0x7FFF + ((u >> 16) & 1)) >> 16;
  return (unsigned short)r;
}

__device__ __forceinline__ void async16(const void* g, void* l) {
  __builtin_amdgcn_global_load_lds(
      (const __attribute__((address_space(1))) unsigned int*)(g),
      (__attribute__((address_space(3))) unsigned int*)(l), 16, 0, 0);
}

// Sum across the 16 lanes of a DPP row (lanes 16k..16k+15) via row_ror.
__device__ __forceinline__ float rowsum16(float x) {
  x += __int_as_float(__builtin_amdgcn_update_dpp(0, __float_as_int(x), 0x121, 0xF, 0xF, false));
  x += __int_as_float(__builtin_amdgcn_update_dpp(0, __float_as_int(x), 0x122, 0xF, 0xF, false));
  x += __int_as_float(__builtin_amdgcn_update_dpp(0, __float_as_int(x), 0x124, 0xF, 0xF, false));
  x += __int_as_float(__builtin_amdgcn_update_dpp(0, __float_as_int(x), 0x128, 0xF, 0xF, false));
  return x;
}

// ---------------------------------------------------------------------------
// fp32 -> bf16 converts: x,R,K,V fused (R/K/V into one concatenated 3072x2048).
// ---------------------------------------------------------------------------
__global__ __launch_bounds__(256) void cvt4_kernel(
    const float* __restrict__ x, const float* __restrict__ R,
    const float* __restrict__ K, const float* __restrict__ V,
    unsigned short* __restrict__ xb, unsigned short* __restrict__ RKVb)
{
  const int bid = blockIdx.x;
  const float* s; unsigned short* d; int i;
  if (bid < 8192)       { s = x; d = xb; i = bid * 256 + threadIdx.x; }
  else if (bid < 12288) { s = R; d = RKVb; i = (bid - 8192) * 256 + threadIdx.x; }
  else if (bid < 13312) { s = K; d = RKVb + 2048 * 2048; i = (bid - 12288) * 256 + threadIdx.x; }
  else                  { s = V; d = RKVb + 2560 * 2048; i = (bid - 13312) * 256 + threadIdx.x; }
  float4 v = ((const float4*)s)[i];
  ushort4 o;
  o.x = f2b(v.x); o.y = f2b(v.y); o.z = f2b(v.z); o.w = f2b(v.w);
  ((ushort4*)d)[i] = o;
}

__global__ __launch_bounds__(256) void cvt_bf16(
    const float* __restrict__ s, unsigned short* __restrict__ d, int n4)
{
  int i = blockIdx.x * 256 + threadIdx.x;
  if (i < n4) {
    float4 v = ((const float4*)s)[i];
    ushort4 o;
    o.x = f2b(v.x); o.y = f2b(v.y); o.z = f2b(v.z); o.w = f2b(v.w);
    ((ushort4*)d)[i] = o;
  }
}

// ---------------------------------------------------------------------------
// Transposed convert: out[n*ors + k] = bf16(in[k*Nd + n]).
// ---------------------------------------------------------------------------
__global__ __launch_bounds__(256) void tcvt_kernel(
    const float* __restrict__ in, unsigned short* __restrict__ out,
    int Kd, int Nd, int ors)
{
  __shared__ unsigned short tile[64][65];
  const int tx = threadIdx.x & 63, ty = threadIdx.x >> 6;
  const int n0 = blockIdx.x * 64, k0 = blockIdx.y * 64;
  #pragma unroll
  for (int j = 0; j < 16; ++j) {
    const int k = k0 + j * 4 + ty;
    const int n = n0 + tx;
    unsigned short v = 0;
    if (k < Kd && n < Nd) v = f2b(in[(size_t)k * Nd + n]);
    tile[j * 4 + ty][tx] = v;
  }
  __syncthreads();
  #pragma unroll
  for (int j = 0; j < 16; ++j) {
    const int n = n0 + j * 4 + ty;
    const int k = k0 + tx;
    if (n < Nd && k < Kd) out[(size_t)n * ors + k] = tile[tx][j * 4 + ty];
  }
}

// ---------------------------------------------------------------------------
// bf16 MFMA GEMM: C[M,N] = A[M,K] @ B[N,K]^T (+bias). 128x128 tile, BK=32.
// ---------------------------------------------------------------------------
template<int OUTBF16, int ACT>
__global__ __launch_bounds__(256) void gemm_mfma(
    const unsigned short* __restrict__ A, int lda,
    const unsigned short* __restrict__ B, int ldb,
    const float* __restrict__ bias, void* __restrict__ Cv, int ldc,
    int M, int N, int K)
{
  __shared__ __align__(16) unsigned short As[128 * 32];
  __shared__ __align__(16) unsigned short Bs[128 * 32];
  const int tid = threadIdx.x;
  const int w = tid >> 6, lane = tid & 63;
  const int wr = (w >> 1) * 64, wc = (w & 1) * 64;
  const int row0 = blockIdx.y * 128, col0 = blockIdx.x * 128;

  f32x4 acc[4][4];
  #pragma unroll
  for (int i = 0; i < 4; ++i)
    #pragma unroll
    for (int j = 0; j < 4; ++j)
      acc[i][j] = (f32x4){0.f, 0.f, 0.f, 0.f};

  const int srow = w * 32 + (lane >> 2);
  const int scol = (lane & 3) * 8;
  const int brow0 = (col0 + srow < N) ? (col0 + srow) : 0;
  const int brow1 = (col0 + srow + 16 < N) ? (col0 + srow + 16) : 0;
  const unsigned short* gA0 = A + (size_t)(row0 + srow) * lda + scol;
  const unsigned short* gA1 = gA0 + (size_t)16 * lda;
  const unsigned short* gB0 = B + (size_t)brow0 * ldb + scol;
  const unsigned short* gB1 = B + (size_t)brow1 * ldb + scol;
  unsigned short* lA0 = As + w * 1024;
  unsigned short* lA1 = As + w * 1024 + 512;
  unsigned short* lB0 = Bs + w * 1024;
  unsigned short* lB1 = Bs + w * 1024 + 512;

  const int m16 = lane & 15;
  const int q8  = (lane >> 4) * 8;

  for (int k0 = 0; k0 < K; k0 += 32) {
    async16(gA0, lA0);
    async16(gA1, lA1);
    async16(gB0, lB0);
    async16(gB1, lB1);
    gA0 += 32; gA1 += 32; gB0 += 32; gB1 += 32;
    __syncthreads();
    bf16x8 af[4], bfr[4];
    #pragma unroll
    for (int i = 0; i < 4; ++i) {
      af[i]  = *(const bf16x8*)(As + (wr + i * 16 + m16) * 32 + q8);
      bfr[i] = *(const bf16x8*)(Bs + (wc + i * 16 + m16) * 32 + q8);
    }
    #pragma unroll
    for (int i = 0; i < 4; ++i)
      #pragma unroll
      for (int j = 0; j < 4; ++j)
        acc[i][j] = __builtin_amdgcn_mfma_f32_16x16x32_bf16(af[i], bfr[j], acc[i][j], 0, 0, 0);
    __syncthreads();
  }

  #pragma unroll
  for (int j = 0; j < 4; ++j) {
    const int c_ = col0 + wc + j * 16 + (lane & 15);
    if (c_ < N) {
      const float bv = bias ? bias[c_] : 0.f;
      #pragma unroll
      for (int i = 0; i < 4; ++i) {
        const int r_ = row0 + wr + i * 16 + (lane >> 4) * 4;
        #pragma unroll
        for (int t4 = 0; t4 < 4; ++t4) {
          float v = acc[i][j][t4] + bv;
          if (ACT == 2 && c_ < 64) v = tanhf(v);
          if (OUTBF16)
            ((unsigned short*)Cv)[(size_t)(r_ + t4) * ldc + c_] = f2b(v);
          else
            ((float*)Cv)[(size_t)(r_ + t4) * ldc + c_] = v;
        }
      }
    }
  }
}

// ---------------------------------------------------------------------------
// Merged R|K|V projection GEMM: B is the concatenated (3072 x 2048) weight.
// Region (R: cols 0..2047 / K: 2048..2559 / V: 2560..3071) is uniform per
// block because region widths are multiples of 128.
// ---------------------------------------------------------------------------
__global__ __launch_bounds__(256) void gemm_rkv(
    const unsigned short* __restrict__ A, const unsigned short* __restrict__ B,
    const float* __restrict__ Rb_, const float* __restrict__ Kb_,
    const float* __restrict__ Vb_,
    float* __restrict__ Cr, float* __restrict__ Ck, float* __restrict__ Cvv)
{
  __shared__ __align__(16) unsigned short As[128 * 32];
  __shared__ __align__(16) unsigned short Bs[128 * 32];
  const int tid = threadIdx.x;
  const int w = tid >> 6, lane = tid & 63;
  const int wr = (w >> 1) * 64, wc = (w & 1) * 64;
  const int row0 = blockIdx.y * 128, col0 = blockIdx.x * 128;

  float* Cd; int ldc, cbase; const float* bias;
  if (col0 < 2048)      { Cd = Cr;  ldc = 2048; cbase = col0;        bias = Rb_; }
  else if (col0 < 2560) { Cd = Ck;  ldc = 512;  cbase = col0 - 2048; bias = Kb_; }
  else                  { Cd = Cvv; ldc = 512;  cbase = col0 - 2560; bias = Vb_; }

  f32x4 acc[4][4];
  #pragma unroll
  for (int i = 0; i < 4; ++i)
    #pragma unroll
    for (int j = 0; j < 4; ++j)
      acc[i][j] = (f32x4){0.f, 0.f, 0.f, 0.f};

  const int srow = w * 32 + (lane >> 2);
  const int scol = (lane & 3) * 8;
  const unsigned short* gA0 = A + (size_t)(row0 + srow) * 2048 + scol;
  const unsigned short* gA1 = gA0 + (size_t)16 * 2048;
  const unsigned short* gB0 = B + (size_t)(col0 + srow) * 2048 + scol;
  const unsigned short* gB1 = gB0 + (size_t)16 * 2048;
  unsigned short* lA0 = As + w * 1024;
  unsigned short* lA1 = As + w * 1024 + 512;
  unsigned short* lB0 = Bs + w * 1024;
  unsigned short* lB1 = Bs + w * 1024 + 512;

  const int m16 = lane & 15;
  const int q8  = (lane >> 4) * 8;

  for (int k0 = 0; k0 < 2048; k0 += 32) {
    async16(gA0, lA0);
    async16(gA1, lA1);
    async16(gB0, lB0);
    async16(gB1, lB1);
    gA0 += 32; gA1 += 32; gB0 += 32; gB1 += 32;
    __syncthreads();
    bf16x8 af[4], bfr[4];
    #pragma unroll
    for (int i = 0; i < 4; ++i) {
      af[i]  = *(const bf16x8*)(As + (wr + i * 16 + m16) * 32 + q8);
      bfr[i] = *(const bf16x8*)(Bs + (wc + i * 16 + m16) * 32 + q8);
    }
    #pragma unroll
    for (int i = 0; i < 4; ++i)
      #pragma unroll
      for (int j = 0; j < 4; ++j)
        acc[i][j] = __builtin_amdgcn_mfma_f32_16x16x32_bf16(af[i], bfr[j], acc[i][j], 0, 0, 0);
    __syncthreads();
  }

  #pragma unroll
  for (int j = 0; j < 4; ++j) {
    const int c_ = cbase + wc + j * 16 + (lane & 15);
    const float bv = bias[c_];
    #pragma unroll
    for (int i = 0; i < 4; ++i) {
      const int r_ = row0 + wr + i * 16 + (lane >> 4) * 4;
      #pragma unroll
      for (int t4 = 0; t4 < 4; ++t4)
        Cd[(size_t)(r_ + t4) * ldc + c_] = acc[i][j][t4] + bv;
    }
  }
}

// ---------------------------------------------------------------------------
// Elementwise prep (unchanged).
// ---------------------------------------------------------------------------
__global__ __launch_bounds__(256) void prep_kernel(
    const float* __restrict__ k_buf, const float* __restrict__ v_buf,
    float* wt_decay, const float* __restrict__ at, float* vt_vf,
    const float* __restrict__ v_first,
    const float* __restrict__ w0, const float* __restrict__ a0,
    const float* __restrict__ v0, const float* __restrict__ k_k,
    const float* __restrict__ k_a,
    float* __restrict__ kf, float* __restrict__ aaq, float* __restrict__ bbq)
{
  const int row = blockIdx.x;
  const int tid = threadIdx.x;
  const int c0 = tid << 3;
  const int h = tid >> 3;
  const int kvoff = (h >> 2) << 6;
  const size_t base = (size_t)row * 2048;
  const size_t kvrow = (size_t)row * 512;
  float kr[8], kkr[8];
  float ss = 0.f;
  #pragma unroll
  for (int e = 0; e < 8; ++e) {
    const int c = c0 + e;
    const float kv = k_buf[kvrow + kvoff + (c & 63)];
    kr[e] = kv;
    const float t = kv * k_k[c];
    kkr[e] = t;
    ss = fmaf(t, t, ss);
  }
  ss += __shfl_xor(ss, 1);
  ss += __shfl_xor(ss, 2);
  ss += __shfl_xor(ss, 4);
  const float inv = 1.f / fmaxf(sqrtf(ss), 1e-12f);
  #pragma unroll
  for (int e = 0; e < 8; ++e) {
    const int c = c0 + e;
    const size_t idx = base + c;
    const float kk = kkr[e] * inv;
    const float a = 1.f / (1.f + expf(-(a0[c] + at[idx])));
    const float u = w0[c] + wt_decay[idx];
    const float sig_u = 1.f / (1.f + expf(-u));
    wt_decay[idx] = expf(-0.5488116360940264f * sig_u);
    kf[idx] = kr[e] * fmaf(a - 1.f, k_a[c], 1.f);
    const float vr = v_buf[kvrow + kvoff + (c & 63)];
    const float sv = 1.f / (1.f + expf(-(v0[c] + vt_vf[idx])));
    vt_vf[idx] = vr + (v_first[idx] - vr) * sv;
    aaq[idx] = -kk;
    bbq[idx] = kk * a;
  }
}

// ---------------------------------------------------------------------------
// RWKV-7 scan — row-parallel, barrier-free. 2048 independent waves: wave
// (bh, g) owns rows 4g..4g+3 of state S[bh]. Lane: row = 4g + (lane>>4),
// cols 4*(lane&15)..+3. sa/y reductions are 16-lane DPP row_ror sums.
// Distance-2 register prefetch of the 6 per-step streams.
// ---------------------------------------------------------------------------
__global__ __launch_bounds__(256) void scan_kernel(
    const float* __restrict__ rB, const float* __restrict__ dB,
    const float* __restrict__ kB, const float* __restrict__ vB,
    const float* __restrict__ aB, const float* __restrict__ bB,
    const float* __restrict__ state, float* __restrict__ y)
{
  const int tid = threadIdx.x;
  const int wave = (blockIdx.x << 2) + (tid >> 6);
  const int bh = wave >> 4;
  const int g = wave & 15;
  const int b = bh >> 5, h = bh & 31;
  const int lane = tid & 63;
  const int row = (g << 2) + (lane >> 4);
  const int colg = lane & 15;

  float4 S = *(const float4*)(state + (size_t)bh * 4096 + row * 64 + (colg << 2));

  const unsigned cb = (unsigned)((b * 1024) * 2048 + h * 64);
  unsigned vo = cb + (colg << 2);   // vector streams (float index)
  unsigned vs = cb + row;           // v-stream / y-store index

  float4 af[2], df[2], bf[2], kq[2], rq[2]; float vq[2];
  af[0] = *(const float4*)(aB + vo);  af[1] = *(const float4*)(aB + vo + 2048);
  df[0] = *(const float4*)(dB + vo);  df[1] = *(const float4*)(dB + vo + 2048);
  bf[0] = *(const float4*)(bB + vo);  bf[1] = *(const float4*)(bB + vo + 2048);
  kq[0] = *(const float4*)(kB + vo);  kq[1] = *(const float4*)(kB + vo + 2048);
  rq[0] = *(const float4*)(rB + vo);  rq[1] = *(const float4*)(rB + vo + 2048);
  vq[0] = vB[vs]; vq[1] = vB[vs + 2048];

  unsigned pf = vo + 2 * 2048;
  unsigned ps = vs + 2 * 2048;
  unsigned yo = vs;

  #pragma unroll 4
  for (int t = 0; t < 1024; ++t) {
    const int p = t & 1;
    const float4 av = af[p], dv = df[p], bv = bf[p], kv = kq[p], rv = rq[p];
    const float vv = vq[p];
    if (t < 1022) {   // prefetch step t+2 into the slot just consumed
      af[p] = *(const float4*)(aB + pf);
      df[p] = *(const float4*)(dB + pf);
      bf[p] = *(const float4*)(bB + pf);
      kq[p] = *(const float4*)(kB + pf);
      rq[p] = *(const float4*)(rB + pf);
      vq[p] = vB[ps];
      pf += 2048; ps += 2048;
    }
    float t0 = fmaf(S.y, av.y, S.x * av.x);
    t0 = fmaf(S.z, av.z, t0);
    t0 = fmaf(S.w, av.w, t0);
    const float sa = rowsum16(t0);
    S.x = fmaf(S.x, dv.x, fmaf(sa, bv.x, vv * kv.x));
    S.y = fmaf(S.y, dv.y, fmaf(sa, bv.y, vv * kv.y));
    S.z = fmaf(S.z, dv.z, fmaf(sa, bv.z, vv * kv.z));
    S.w = fmaf(S.w, dv.w, fmaf(sa, bv.w, vv * kv.w));
    float t1 = fmaf(S.y, rv.y, S.x * rv.x);
    t1 = fmaf(S.z, rv.z, t1);
    t1 = fmaf(S.w, rv.w, t1);
    const float yv = rowsum16(t1);
    if (colg == 0) y[yo] = yv;
    yo += 2048;
  }
}

// ---------------------------------------------------------------------------
// GroupNorm pass A: partial sums per (bh, seg of 128 t-rows) -> part[blk].
// ---------------------------------------------------------------------------
__global__ __launch_bounds__(256) void gsum_kernel(
    const float* __restrict__ y, float* __restrict__ part)
{
  const int blk = blockIdx.x;        // bh*8 + seg
  const int bh = blk >> 3, seg = blk & 7;
  const int b = bh >> 5, h = bh & 31;
  const int tid = threadIdx.x;
  const size_t base = ((size_t)(b * 1024 + seg * 128)) * 2048 + h * 64;
  float s = 0.f, ss = 0.f;
  for (int i = tid; i < 8192; i += 256) {
    const int t = i >> 6, n = i & 63;
    const float v = y[base + (size_t)t * 2048 + n];
    s += v;
    ss = fmaf(v, v, ss);
  }
  #pragma unroll
  for (int o = 1; o < 64; o <<= 1) {
    s  += __shfl_xor(s, o);
    ss += __shfl_xor(ss, o);
  }
  __shared__ float red[8];
  const int wid = tid >> 6;
  if ((tid & 63) == 0) { red[wid] = s; red[4 + wid] = ss; }
  __syncthreads();
  if (tid == 0) {
    const float st  = red[0] + red[1] + red[2] + red[3];
    const float sst = red[4] + red[5] + red[6] + red[7];
    ((float2*)part)[blk] = make_float2(st, sst);
  }
}

// ---------------------------------------------------------------------------
// GroupNorm pass B + bonus: per-(b,t) row, writes xx in bf16.
// ---------------------------------------------------------------------------
__global__ __launch_bounds__(256) void gapply_kernel(
    const float* __restrict__ y, const float* __restrict__ rB,
    const float* __restrict__ kf, const float* __restrict__ vf,
    const float* __restrict__ part, const float* __restrict__ r_k,
    const float* __restrict__ ln_w, const float* __restrict__ ln_b,
    unsigned short* __restrict__ xxb)
{
  const int row = blockIdx.x;        // b*1024 + t
  const int b = row >> 10;
  const int tid = threadIdx.x;
  const int h = tid >> 3;
  const int bh = b * 32 + h;
  float s = 0.f, ss = 0.f;
  #pragma unroll
  for (int j = 0; j < 8; ++j) {
    const float2 pr = ((const float2*)part)[(bh << 3) + j];
    s += pr.x; ss += pr.y;
  }
  const float mean = s * (1.f / 65536.f);
  const float rstd = rsqrtf(ss * (1.f / 65536.f) - mean * mean + 0.00064f);
  const int c0 = tid << 3;
  const size_t base = (size_t)row * 2048 + c0;
  float yv[8], vv[8];
  float p = 0.f;
  #pragma unroll
  for (int e = 0; e < 8; ++e) {
    yv[e] = y[base + e];
    vv[e] = vf[base + e];
    p = fmaf(rB[base + e] * kf[base + e], r_k[c0 + e], p);
  }
  p += __shfl_xor(p, 1);
  p += __shfl_xor(p, 2);
  p += __shfl_xor(p, 4);
  #pragma unroll
  for (int e = 0; e < 8; ++e) {
    const float yn = (yv[e] - mean) * rstd;
    xxb[base + e] = f2b(fmaf(yn, ln_w[c0 + e], ln_b[c0 + e]) + p * vv[e]);
  }
}

// ---------------------------------------------------------------------------
extern "C" void kernel_launch(void* const* d_in, const int* in_sizes, int n_in,
                              void* d_out, int out_size, void* d_ws, size_t ws_size,
                              hipStream_t stream) {
  const float* x       = (const float*)d_in[0];
  const float* v_first = (const float*)d_in[1];
  const float* state   = (const float*)d_in[2];
  const float* Rw      = (const float*)d_in[3];
  const float* R_bias  = (const float*)d_in[4];
  const float* Kw      = (const float*)d_in[5];
  const float* K_bias  = (const float*)d_in[6];
  const float* Vw      = (const float*)d_in[7];
  const float* V_bias  = (const float*)d_in[8];
  const float* Ow      = (const float*)d_in[9];
  const float* O_bias  = (const float*)d_in[10];
  const float* w0      = (const float*)d_in[11];
  const float* w1      = (const float*)d_in[12];
  const float* w2      = (const float*)d_in[13];
  const float* a0      = (const float*)d_in[14];
  const float* a1      = (const float*)d_in[15];
  const float* a2      = (const float*)d_in[16];
  const float* v0      = (const float*)d_in[17];
  const float* v1      = (const float*)d_in[18];
  const float* v2      = (const float*)d_in[19];
  const float* k_k     = (const float*)d_in[20];
  const float* k_a     = (const float*)d_in[21];
  const float* r_k     = (const float*)d_in[22];
  const float* ln_w    = (const float*)d_in[23];
  const float* ln_b    = (const float*)d_in[24];

  float* ws = (float*)d_ws;
  float* r_buf = ws;                    // 8388608
  float* k_buf = r_buf + 8388608;       // 2097152
  float* v_buf = k_buf + 2097152;       // 2097152
  float* wt    = v_buf + 2097152;       // 8388608 (u -> decay in place)
  float* at    = wt    + 8388608;       // 8388608 (a pre-act -> y after scan)
  float* vt    = at    + 8388608;       // 8388608 (v pre-act -> v_final)
  float* kf    = vt    + 8388608;       // 8388608
  float* aaq   = kf    + 8388608;       // 8388608
  float* bbq   = aaq   + 8388608;       // 8388608
  float* part  = bbq   + 8388608;       // 2048 (gnorm partials)
  // bf16 aliases into dead-at-use regions (all 16B-aligned):
  unsigned short* xb   = (unsigned short*)bbq;               // dead until prep
  unsigned short* RKVb = (unsigned short*)kf;                // 3072x2048 bf16
  unsigned short* hcat = (unsigned short*)(kf + 3200000);    // 4096x160 bf16
  unsigned short* Bcat = (unsigned short*)(kf + 3600000);    // 160x2048 bf16
  unsigned short* w2t  = (unsigned short*)(kf + 3800000);    // 2048x64
  unsigned short* a2t  = (unsigned short*)(kf + 3900000);    // 2048x64
  unsigned short* v2t  = (unsigned short*)(kf + 4000000);    // 2048x32
  unsigned short* Ob   = (unsigned short*)wt;                // after scan
  unsigned short* xxb  = (unsigned short*)aaq;               // after scan

  dim3 blk(256);
  // ---- converts ----
  cvt4_kernel<<<14336, blk, 0, stream>>>(x, Rw, Kw, Vw, xb, RKVb);
  tcvt_kernel<<<dim3(1, 32), blk, 0, stream>>>(w1, Bcat,              2048, 64, 2048);
  tcvt_kernel<<<dim3(1, 32), blk, 0, stream>>>(a1, Bcat + 64 * 2048,  2048, 64, 2048);
  tcvt_kernel<<<dim3(1, 32), blk, 0, stream>>>(v1, Bcat + 128 * 2048, 2048, 32, 2048);
  tcvt_kernel<<<dim3(32, 1), blk, 0, stream>>>(w2, w2t, 64, 2048, 64);
  tcvt_kernel<<<dim3(32, 1), blk, 0, stream>>>(a2, a2t, 64, 2048, 64);
  tcvt_kernel<<<dim3(32, 1), blk, 0, stream>>>(v2, v2t, 32, 2048, 32);
  // ---- low-rank stage 1 (fused, bf16 out, tanh on w-cols) ----
  gemm_mfma<1,2><<<dim3(2, 32), blk, 0, stream>>>(xb, 2048, Bcat, 2048, nullptr,
                                                  hcat, 160, 4096, 160, 2048);
  // ---- merged R|K|V projection ----
  gemm_rkv<<<dim3(24, 32), blk, 0, stream>>>(xb, RKVb, R_bias, K_bias, V_bias,
                                             r_buf, k_buf, v_buf);
  // ---- low-rank stage 2 ----
  gemm_mfma<0,0><<<dim3(16, 32), blk, 0, stream>>>(hcat, 160, w2t, 64, nullptr,
                                                   wt, 2048, 4096, 2048, 64);
  gemm_mfma<0,0><<<dim3(16, 32), blk, 0, stream>>>(hcat + 64, 160, a2t, 64, nullptr,
                                                   at, 2048, 4096, 2048, 64);
  gemm_mfma<0,0><<<dim3(16, 32), blk, 0, stream>>>(hcat + 128, 160, v2t, 32, nullptr,
                                                   vt, 2048, 4096, 2048, 32);
  // ---- elementwise prep ----
  prep_kernel<<<4096, blk, 0, stream>>>(k_buf, v_buf, wt, at, vt, v_first,
                                        w0, a0, v0, k_k, k_a, kf, aaq, bbq);
  // ---- recurrent scan (row-parallel; y reuses `at`) ----
  float* ybuf = at;
  scan_kernel<<<512, blk, 0, stream>>>(r_buf, wt, kf, vt, aaq, bbq, state, ybuf);
  // ---- O weight convert (wt dead after scan) ----
  cvt_bf16<<<4096, blk, 0, stream>>>(Ow, Ob, 1048576);
  // ---- group norm (two passes) + bonus -> bf16 xx ----
  gsum_kernel<<<1024, blk, 0, stream>>>(ybuf, part);
  gapply_kernel<<<4096, blk, 0, stream>>>(ybuf, r_buf, kf, vt, part, r_k,
                                          ln_w, ln_b, xxb);
  // ---- output projection ----
  gemm_mfma<0,0><<<dim3(16, 32), blk, 0, stream>>>(xxb, 2048, Ob, 2048, O_bias,
                                                   (float*)d_out, 2048, 4096, 2048, 2048);
}